// Round 11
// baseline (105.789 us; speedup 1.0000x reference)
//
#include <hip/hip_runtime.h>
#include <hip/hip_bf16.h>
#include <stdint.h>

typedef __attribute__((ext_vector_type(4))) float f32x4;
typedef __attribute__((ext_vector_type(8))) short short8;

#define NN 4096      // nodes
#define FIN 128
#define FHID 64
#define BATCH 32
#define NJ 2048      // BATCH * FHID

// ---------- helpers ----------
__device__ __forceinline__ unsigned short f2bf(float f) {
  unsigned u = __builtin_bit_cast(unsigned, f);
  u = (u + 0x7FFFu + ((u >> 16) & 1u)) >> 16;   // RNE
  return (unsigned short)u;
}
__device__ __forceinline__ float bf2f(unsigned short h) {
  unsigned u = ((unsigned)h) << 16;
  return __builtin_bit_cast(float, u);
}
__device__ __forceinline__ void gload_lds16(const void* g, void* l) {
  __builtin_amdgcn_global_load_lds(
      (const __attribute__((address_space(1))) unsigned int*)g,
      (__attribute__((address_space(3))) unsigned int*)l, 16, 0, 0);
}

// ---------- K0: adj fp32 -> bf16 ----------
__global__ __launch_bounds__(256) void k_convert(const float* __restrict__ adj,
                                                 unsigned short* __restrict__ adjb) {
  long i = (long)blockIdx.x * 256 + threadIdx.x;
  const f32x4* in = (const f32x4*)adj;
  f32x4 v = in[i];
  ushort4 o;
  o.x = f2bf(v.x); o.y = f2bf(v.y); o.z = f2bf(v.z); o.w = f2bf(v.w);
  *(ushort4*)(adjb + i * 4) = o;
}

// ---------- K1: St[b*64+h][m] = sum_f x[b][m][f] * W1[f][h]  (bf16 out) ----------
__global__ __launch_bounds__(256) void k_support(const float* __restrict__ x,
                                                 const float* __restrict__ W1,
                                                 unsigned short* __restrict__ St) {
  __shared__ unsigned short W1t[FHID * 136];              // [h][f], pad 136
  __shared__ __align__(16) unsigned short T[FHID * 128];  // [h][m_loc]
  const int tid = threadIdx.x;
  for (int i = tid; i < FIN * FHID; i += 256) {
    int f = i >> 6, h = i & 63;
    W1t[h * 136 + f] = f2bf(W1[i]);
  }
  __syncthreads();

  const int bb = blockIdx.x >> 5;
  const int m0 = (blockIdx.x & 31) * 128;
  const int lane = tid & 63, wv = tid >> 6;
  const int fr = lane & 15, fq = lane >> 4;

  short8 bfr[4][4];
  #pragma unroll
  for (int ni = 0; ni < 4; ++ni)
    #pragma unroll
    for (int ks = 0; ks < 4; ++ks)
      bfr[ni][ks] = *(const short8*)&W1t[(ni * 16 + fr) * 136 + ks * 32 + fq * 8];

  const float* xr0 = x + ((size_t)bb * NN + m0 + wv * 32 + fr) * FIN;
  const float* xr1 = xr0 + (size_t)16 * FIN;

  f32x4 z = {0.f, 0.f, 0.f, 0.f};
  f32x4 acc[2][4];
  #pragma unroll
  for (int mf = 0; mf < 2; ++mf)
    #pragma unroll
    for (int ni = 0; ni < 4; ++ni) acc[mf][ni] = z;

  #pragma unroll
  for (int ks = 0; ks < 4; ++ks) {
    #pragma unroll
    for (int mf = 0; mf < 2; ++mf) {
      const float* src = (mf ? xr1 : xr0) + ks * 32 + fq * 8;
      f32x4 lo = *(const f32x4*)src;
      f32x4 hi = *(const f32x4*)(src + 4);
      short8 a;
      #pragma unroll
      for (int j = 0; j < 4; ++j) { a[j] = (short)f2bf(lo[j]); a[4 + j] = (short)f2bf(hi[j]); }
      #pragma unroll
      for (int ni = 0; ni < 4; ++ni)
        acc[mf][ni] = __builtin_amdgcn_mfma_f32_16x16x32_bf16(a, bfr[ni][ks], acc[mf][ni], 0, 0, 0);
    }
  }

  const int cr = (lane >> 4) * 4, cc = lane & 15;
  #pragma unroll
  for (int mf = 0; mf < 2; ++mf)
    #pragma unroll
    for (int ni = 0; ni < 4; ++ni) {
      ushort4 o;
      o.x = f2bf(acc[mf][ni][0]); o.y = f2bf(acc[mf][ni][1]);
      o.z = f2bf(acc[mf][ni][2]); o.w = f2bf(acc[mf][ni][3]);
      *(ushort4*)&T[(ni * 16 + cc) * 128 + wv * 32 + mf * 16 + cr] = o;
    }
  __syncthreads();
  for (int u = tid; u < FHID * 16; u += 256) {
    int row = u >> 4, ch = u & 15;
    *(short8*)(St + (size_t)(bb * FHID + row) * NN + m0 + ch * 8) =
        *(const short8*)&T[row * 128 + ch * 8];
  }
}

// ---------- K2: fused GEMM + bias + relu + row-weighted aggregation ----------
// 128x128 tile, BK=64, 4 waves (2M x 2N), per-wave 64x64, dbuf LDS 64 KB
// -> 2 blocks/CU (TLP hides barrier/vmcnt stalls). R5-proven 4-phase
// single-barrier schedule, reg-dbuf bvA, one counted vmcnt(6)/tile,
// XOR-swizzle via pre-swizzled global source. Epilogue: weight
// relu(acc+bias) by adj[q_b][row], reduce -> partial[rowblock][col].
#define VMW(N)  asm volatile("s_waitcnt vmcnt(" #N ")" ::: "memory")
#define LGKM0   asm volatile("s_waitcnt lgkmcnt(0)" ::: "memory")
#define BAR     __builtin_amdgcn_s_barrier()

__global__ __launch_bounds__(256, 2) void k_gemm(const unsigned short* __restrict__ A,
                                                 const unsigned short* __restrict__ Bt,
                                                 const float* __restrict__ b1,
                                                 const float* __restrict__ adj,
                                                 const int* __restrict__ q_ids,
                                                 float* __restrict__ partial) {
  __shared__ __align__(16) unsigned short As[2 * 8192];   // A: 128x64 dbuf, 32 KB
  __shared__ __align__(16) unsigned short Bs[2 * 8192];   // B: 128x64 dbuf, 32 KB
  __shared__ float adjw[2][128];                          // 1 KB (epilogue)
  __shared__ float red[4][64];                            // 1 KB (epilogue)

  const int tid  = threadIdx.x;
  const int lane = tid & 63;
  const int wv   = tid >> 6;         // 4 waves: 2M x 2N
  const int wm   = wv >> 1;          // 0..1 (M)
  const int wn   = wv & 1;           // 0..1 (N)
  const int bm   = blockIdx.x * 128;
  const int bn   = blockIdx.y * 128;
  const int fr   = lane & 15;
  const int fq   = lane >> 4;

  // fragment LDS ushort offsets (buffer-relative)
  // A rows: wm*64 + h*32 + m2*16 ; B rows: wn*64 + (ni>>1)*32 + (ni&1)*16
  int offA[2][2][2], offB[4][2];
  #pragma unroll
  for (int h = 0; h < 2; ++h)
    #pragma unroll
    for (int m2 = 0; m2 < 2; ++m2) {
      int row = wm * 64 + h * 32 + m2 * 16 + fr;
      #pragma unroll
      for (int ks = 0; ks < 2; ++ks)
        offA[h][m2][ks] = row * 64 + ((((ks << 6) + (fq << 4)) ^ ((row & 7) << 4)) >> 1);
    }
  #pragma unroll
  for (int ni = 0; ni < 4; ++ni) {
    int row = wn * 64 + (ni >> 1) * 32 + (ni & 1) * 16 + fr;
    #pragma unroll
    for (int ks = 0; ks < 2; ++ks)
      offB[ni][ks] = row * 64 + ((((ks << 6) + (fq << 4)) ^ ((row & 7) << 4)) >> 1);
  }

  // staging: 8 chunks of 32 rows (A c0..3, B c0..3); thread covers 1 slot/chunk
  const int srow = tid >> 3;                              // 0..31
  const int scol = ((((tid & 7) << 4) ^ ((srow & 7) << 4)) >> 1);
  const unsigned short* gA[4];
  const unsigned short* gB[4];
  #pragma unroll
  for (int c = 0; c < 4; ++c) {
    gA[c] = A  + (size_t)(bm + 32 * c + srow) * NN + scol;
    gB[c] = Bt + (size_t)(bn + 32 * c + srow) * NN + scol;
  }
  const int ld = tid * 8;   // ushort offset of thread's 16B slot within a chunk? no: within tile

  f32x4 z = {0.f, 0.f, 0.f, 0.f};
  f32x4 acc[4][4];
  #pragma unroll
  for (int i = 0; i < 4; ++i)
    #pragma unroll
    for (int j = 0; j < 4; ++j) acc[i][j] = z;

  short8 av0[2][2], av1[2][2], bvB[2][2], bvA0[2][2], bvA1[2][2];

#define RD_AVA(Ac)                                                             \
    _Pragma("unroll") for (int m2 = 0; m2 < 2; ++m2)                           \
    _Pragma("unroll") for (int ks = 0; ks < 2; ++ks)                           \
      av0[m2][ks] = *(const short8*)((Ac) + offA[0][m2][ks]);
#define RD_AVB(Ac)                                                             \
    _Pragma("unroll") for (int m2 = 0; m2 < 2; ++m2)                           \
    _Pragma("unroll") for (int ks = 0; ks < 2; ++ks)                           \
      av1[m2][ks] = *(const short8*)((Ac) + offA[1][m2][ks]);
#define RD_BV(DST, Bb, P)                                                      \
    _Pragma("unroll") for (int n2 = 0; n2 < 2; ++n2)                           \
    _Pragma("unroll") for (int ks = 0; ks < 2; ++ks)                           \
      DST[n2][ks] = *(const short8*)((Bb) + offB[2 * (P) + n2][ks]);
#define MFMA8(MP, AV, BV, NP)                                                  \
    __builtin_amdgcn_s_setprio(1);                                             \
    _Pragma("unroll") for (int m2 = 0; m2 < 2; ++m2)                           \
    _Pragma("unroll") for (int n2 = 0; n2 < 2; ++n2)                           \
    _Pragma("unroll") for (int ks = 0; ks < 2; ++ks)                           \
      acc[2 * (MP) + m2][2 * (NP) + n2] = __builtin_amdgcn_mfma_f32_16x16x32_bf16( \
          AV[m2][ks], BV[n2][ks], acc[2 * (MP) + m2][2 * (NP) + n2], 0, 0, 0); \
    __builtin_amdgcn_s_setprio(0);
// chunk c of A/B in buffer BUF: ushort base BUF*8192 + c*2048
#define SG_A(C, KO, BUF) gload_lds16(gA[C] + (KO), As + (BUF) * 8192 + (C) * 2048 + ld);
#define SG_B(C, KO, BUF) gload_lds16(gB[C] + (KO), Bs + (BUF) * 8192 + (C) * 2048 + ld);

// One K-tile, 4 single-barrier phases (R5 guards, 128^2 geometry):
// A-h0 = chunks {0,2} (read P0), A-h1 = chunks {1,3} (read P2),
// B np0 = chunks {0,2} (read prev-P3 as bvA), B np1 = chunks {1,3} (read P1).
// Stages (t+2 -> CUR buf): P1: A0,A2,B0,B2 ; P2: B1,B3 ; P3: A1,A3.
// Steady-state wait at P3: VMW(6) (6 loads issued after t+1's last stage).
#define TILE(CUR, BVA_C, BVA_N, KQ, DOS, VMWOP) {                              \
    const unsigned short* Ac = As + (CUR) * 8192;                              \
    const unsigned short* Bc = Bs + (CUR) * 8192;                              \
    const unsigned short* Bn = Bs + (1 - (CUR)) * 8192;                        \
    /* P0: Q(0,0) */                                                           \
    RD_AVA(Ac)                                                                 \
    BAR; LGKM0;                                                                \
    MFMA8(0, av0, BVA_C, 0)                                                    \
    /* P1: Q(0,1); stage A0,A2,B0,B2(t+2) */                                   \
    RD_BV(bvB, Bc, 1)                                                          \
    if (DOS) { SG_A(0, KQ, CUR) SG_A(2, KQ, CUR)                               \
               SG_B(0, KQ, CUR) SG_B(2, KQ, CUR) }                             \
    BAR; LGKM0;                                                                \
    MFMA8(0, av0, bvB, 1)                                                      \
    /* P2: Q(1,1); stage B1,B3(t+2) */                                         \
    RD_AVB(Ac)                                                                 \
    if (DOS) { SG_B(1, KQ, CUR) SG_B(3, KQ, CUR) }                             \
    BAR; LGKM0;                                                                \
    MFMA8(1, av1, bvB, 1)                                                      \
    /* P3: Q(1,0); vmcnt; stage A1,A3(t+2); read bvA(t+1) post-barrier */      \
    VMWOP;                                                                     \
    if (DOS) { SG_A(1, KQ, CUR) SG_A(3, KQ, CUR) }                             \
    BAR;                                                                       \
    RD_BV(BVA_N, Bn, 0)                                                        \
    MFMA8(1, av1, BVA_C, 0)                                                    \
  }

  // ---- prologue: stage tile0 -> buf0, tile1 -> buf1 (8 gloads each) ----
  #pragma unroll
  for (int c = 0; c < 4; ++c) { SG_A(c, 0, 0) SG_B(c, 0, 0) }
  #pragma unroll
  for (int c = 0; c < 4; ++c) { SG_A(c, 64, 1) SG_B(c, 64, 1) }
  VMW(8);                 // tile0 landed; tile1 in flight
  BAR;
  RD_BV(bvA0, Bs, 0)      // prime bvA for tile 0 (drained at tile0 P0 LGKM0)

  // ---- main loop: 31 macro-iters = tiles 0..61 (stage t+2) ----
  int kq = 128;
  #pragma unroll 1
  for (int g = 0; g < 31; ++g) {
    TILE(0, bvA0, bvA1, kq,      1, VMW(6))
    TILE(1, bvA1, bvA0, kq + 64, 1, VMW(6))
    kq += 128;
  }
  // ---- tile 62 (buf0): no staging; drain for tile 63 ----
  TILE(0, bvA0, bvA1, 0, 0, VMW(0))
  // ---- tile 63 (buf1): last, no bvA-next / no vmcnt ----
  {
    const unsigned short* Ac = As + 8192;
    const unsigned short* Bc = Bs + 8192;
    RD_AVA(Ac)
    BAR; LGKM0;
    MFMA8(0, av0, bvA1, 0)
    RD_BV(bvB, Bc, 1)
    BAR; LGKM0;
    MFMA8(0, av0, bvB, 1)
    RD_AVB(Ac)
    BAR; LGKM0;
    MFMA8(1, av1, bvB, 1)
    MFMA8(1, av1, bvA1, 0)
  }
#undef RD_AVA
#undef RD_AVB
#undef RD_BV
#undef MFMA8
#undef SG_A
#undef SG_B
#undef TILE

  // ---- fused epilogue: bias + relu + weight by adj[q_b][row] + reduce ----
  const int b0 = bn >> 6;            // first batch of this col-block (2 batches)
  {
    int bsel = tid >> 7;             // 0 or 1
    int rloc = tid & 127;
    adjw[bsel][rloc] = adj[(size_t)q_ids[b0 + bsel] * NN + bm + rloc];
  }
  __syncthreads();

  const int cr = (lane >> 4) * 4;
  const int cc = lane & 15;
  float ps[4];
  #pragma unroll
  for (int ni = 0; ni < 4; ++ni) {
    int colh = (ni >> 1) * 32 + (ni & 1) * 16 + cc;   // h index (< 64)
    float bias = b1[colh];
    float s = 0.f;
    #pragma unroll
    for (int mi = 0; mi < 4; ++mi) {
      int rowl = wm * 64 + (mi >> 1) * 32 + (mi & 1) * 16 + cr;
      #pragma unroll
      for (int r = 0; r < 4; ++r) {
        float v = acc[mi][ni][r] + bias;
        v = v > 0.f ? v : 0.f;
        s += adjw[wn][rowl + r] * v;
      }
    }
    ps[ni] = s;
  }
  // reduce across fq groups (lanes differing in bits 4,5)
  #pragma unroll
  for (int ni = 0; ni < 4; ++ni) {
    ps[ni] += __shfl_xor(ps[ni], 16, 64);
    ps[ni] += __shfl_xor(ps[ni], 32, 64);
  }
  if (lane < 16) {
    #pragma unroll
    for (int ni = 0; ni < 4; ++ni)
      red[wv][ni * 16 + cc] = ps[ni];
  }
  __syncthreads();
  if (tid < 128) {
    int wn2 = tid >> 6;
    int ni2 = (((tid >> 5) & 1) << 1) | ((tid >> 4) & 1);
    int sidx = ni2 * 16 + (tid & 15);
    float s = red[0 + wn2][sidx] + red[2 + wn2][sidx];   // sum over wm
    partial[(size_t)blockIdx.x * NJ + bn + tid] = s;
  }
}

// ---------- K4: out[b][l] = sum_h (sum_rb partial[rb][b*64+h]) * W2[h][l] + b2[l] ----------
__global__ __launch_bounds__(1024) void k_out(const float* __restrict__ partial,
                                              const float* __restrict__ W2,
                                              const float* __restrict__ b2,
                                              float* __restrict__ out) {
  __shared__ float aggs[BATCH * FHID];   // 2048
  int t = threadIdx.x;
  for (int idx = t; idx < BATCH * FHID; idx += 1024) {
    float s = 0.f;
    #pragma unroll
    for (int c = 0; c < 32; ++c) s += partial[c * NJ + idx];
    aggs[idx] = s;
  }
  __syncthreads();
  int b = t >> 5, l = t & 31;
  float o = b2[l];
  #pragma unroll
  for (int h = 0; h < FHID; ++h) o += aggs[b * FHID + h] * W2[h * 32 + l];
  out[b * 32 + l] = o;
}

extern "C" void kernel_launch(void* const* d_in, const int* in_sizes, int n_in,
                              void* d_out, int out_size, void* d_ws, size_t ws_size,
                              hipStream_t stream) {
  const float* x   = (const float*)d_in[0];
  const int*   q   = (const int*)d_in[1];
  const float* adj = (const float*)d_in[2];
  const float* W1  = (const float*)d_in[3];
  const float* b1  = (const float*)d_in[4];
  const float* W2  = (const float*)d_in[5];
  const float* b2  = (const float*)d_in[6];
  float* out = (float*)d_out;

  char* ws = (char*)d_ws;
  unsigned short* adjb   = (unsigned short*)ws;                              // 32 MB
  unsigned short* St     = (unsigned short*)(ws + (size_t)32 * 1024 * 1024); // 16 MB
  float*          partial= (float*)(ws + (size_t)48 * 1024 * 1024);          // 256 KB

  // K0: adj -> bf16
  k_convert<<<(NN * NN / 4) / 256, 256, 0, stream>>>(adj, adjb);
  // K1: support^T via MFMA
  k_support<<<1024, 256, 0, stream>>>(x, W1, St);
  // K2: fused GEMM + bias/relu + aggregation (128^2 tiles, 2 blocks/CU)
  dim3 g2(NN / 128, NJ / 128);
  k_gemm<<<g2, 256, 0, stream>>>(adjb, St, b1, adj, q, partial);
  // K3: reduce partials + final tiny GEMM
  k_out<<<1, 1024, 0, stream>>>(partial, W2, b2, out);
}